// Round 1
// baseline (209.022 us; speedup 1.0000x reference)
//
#include <hip/hip_runtime.h>
#include <hip/hip_bf16.h>

typedef __bf16 bf16;
typedef __bf16 bf16x8 __attribute__((ext_vector_type(8)));
typedef __bf16 bf16x4 __attribute__((ext_vector_type(4)));
typedef float  f32x4  __attribute__((ext_vector_type(4)));

#define MFMA16(a,b,c) __builtin_amdgcn_mfma_f32_16x16x32_bf16((a),(b),(c),0,0,0)

// Problem sizes: B=512, T=256, C=512, H=64
// ws layout (bytes):
//   WT  [3][64][512] bf16  @ 0          (196,608)
//   Qw  [B*T][64]    bf16  @ 196608     (16,777,216)
//   Kw  [B*T][64]    bf16  @ 16973824   (16,777,216)
//   VTw [B][64][256] bf16  @ 33751040   (16,777,216)
//   total: 50,528,256 bytes

// ---------------- kernel 0: W [512][64] f32 -> WT [64][512] bf16 (x3) -------
__global__ void __launch_bounds__(256) wt_transpose_kernel(
        const float* __restrict__ Wq, const float* __restrict__ Wk,
        const float* __restrict__ Wv, bf16* __restrict__ WT) {
    int tid = blockIdx.x * 256 + threadIdx.x;        // 3*64*512 = 98304
    int wi = tid >> 15;
    int n  = (tid >> 9) & 63;
    int k  = tid & 511;
    const float* W = (wi == 0) ? Wq : ((wi == 1) ? Wk : Wv);
    WT[tid] = (bf16)W[k * 64 + n];
}

// ---------------- kernel 1: projections -------------------------------------
// grid 1024, block 256 (4 waves). Each wave: 32 rows x 192 cols (q|k|v).
// A-frag: x[m0+mf*16+lo][kc*32+hi*8 .. +8] fp32 -> bf16
// B-frag: WT[nn][kc*32+hi*8 .. +8] (contiguous bf16)
__global__ void __launch_bounds__(256, 2) proj_kernel(
        const float* __restrict__ x, const bf16* __restrict__ WT,
        bf16* __restrict__ Qw, bf16* __restrict__ Kw, bf16* __restrict__ VTw) {
    const int l  = threadIdx.x & 63;
    const int w  = threadIdx.x >> 6;
    const int lo = l & 15;
    const int hi = l >> 4;
    const int m0 = blockIdx.x * 128 + w * 32;

    f32x4 acc[2][12];
    #pragma unroll
    for (int mf = 0; mf < 2; ++mf)
        #pragma unroll
        for (int nf = 0; nf < 12; ++nf)
            acc[mf][nf] = (f32x4){0.f, 0.f, 0.f, 0.f};

    #pragma unroll 2
    for (int kc = 0; kc < 16; ++kc) {
        const int kof = kc * 32 + hi * 8;
        bf16x8 a[2];
        #pragma unroll
        for (int mf = 0; mf < 2; ++mf) {
            const float* p = x + (m0 + mf * 16 + lo) * 512 + kof;
            f32x4 u0 = *(const f32x4*)p;
            f32x4 u1 = *(const f32x4*)(p + 4);
            bf16x8 t;
            t[0] = (bf16)u0[0]; t[1] = (bf16)u0[1]; t[2] = (bf16)u0[2]; t[3] = (bf16)u0[3];
            t[4] = (bf16)u1[0]; t[5] = (bf16)u1[1]; t[6] = (bf16)u1[2]; t[7] = (bf16)u1[3];
            a[mf] = t;
        }
        #pragma unroll
        for (int nf = 0; nf < 12; ++nf) {
            bf16x8 b = *(const bf16x8*)(WT + (nf * 16 + lo) * 512 + kof);
            acc[0][nf] = MFMA16(a[0], b, acc[0][nf]);
            acc[1][nf] = MFMA16(a[1], b, acc[1][nf]);
        }
    }

    // Epilogue. D-frag: n = lo (+nf*16), m = hi*4 + i (+mf*16).
    const int bidx = m0 >> 8;        // batch
    const int t0b  = m0 & 255;       // t base within batch
    #pragma unroll
    for (int nf = 0; nf < 12; ++nf) {
        const int nn = nf * 16 + lo;
        #pragma unroll
        for (int mf = 0; mf < 2; ++mf) {
            const int mrow = m0 + mf * 16 + hi * 4;
            if (nf < 4) {
                #pragma unroll
                for (int i = 0; i < 4; ++i)
                    Qw[(mrow + i) * 64 + nn] = (bf16)acc[mf][nf][i];
            } else if (nf < 8) {
                #pragma unroll
                for (int i = 0; i < 4; ++i)
                    Kw[(mrow + i) * 64 + (nn - 64)] = (bf16)acc[mf][nf][i];
            } else {
                // V stored transposed: VT[b][h][t]; lane's 4 values are consecutive t
                bf16x4 pk;
                pk[0] = (bf16)acc[mf][nf][0]; pk[1] = (bf16)acc[mf][nf][1];
                pk[2] = (bf16)acc[mf][nf][2]; pk[3] = (bf16)acc[mf][nf][3];
                const int t0 = t0b + mf * 16 + hi * 4;
                *(bf16x4*)(VTw + ((bidx * 64 + (nn - 128)) * 256 + t0)) = pk;
            }
        }
    }
}

// ---------------- kernel 2: causal flash attention --------------------------
// grid 512 (one block per batch), block 256 (4 waves).
// Wave w owns q-rows {qf*64 + w*16 + lo} for qf=0..3 (interleaved -> balanced causal work).
// S^T = mfma(A=K, B=Q^T): lane holds S[q=lo][key=hi*4+i] per (kf) frag.
// O^T = mfma(A=V^T, B=P^T): P re-layout via small per-wave LDS buffer.
__global__ void __launch_bounds__(256, 2) attn_kernel(
        const bf16* __restrict__ Qw, const bf16* __restrict__ Kw,
        const bf16* __restrict__ VTw, float* __restrict__ out) {
    __shared__ bf16 Klds[256][72];      // padded: row stride 144B (16B-aligned)
    __shared__ bf16 Plds[4][16][72];    // per-wave P buffer [q(16)][key(64)+pad]

    const int tid = threadIdx.x;
    const int l   = tid & 63;
    const int w   = tid >> 6;
    const int lo  = l & 15;
    const int hi  = l >> 4;
    const int b   = blockIdx.x;

    // Stage K [256][64] -> LDS (coalesced: 8 lanes per row)
    {
        const bf16* src = Kw + b * (256 * 64);
        const int r0 = tid >> 3;
        const int cc = (tid & 7) * 8;
        #pragma unroll
        for (int p = 0; p < 8; ++p) {
            const int row = p * 32 + r0;
            *(bf16x8*)&Klds[row][cc] = *(const bf16x8*)(src + row * 64 + cc);
        }
    }
    __syncthreads();

    // Hoist Q fragments (B-operand of S^T): Q[q][ks*32+hi*8 ..+8]
    bf16x8 qfr[4][2];
    #pragma unroll
    for (int qf = 0; qf < 4; ++qf)
        #pragma unroll
        for (int ks = 0; ks < 2; ++ks)
            qfr[qf][ks] = *(const bf16x8*)(Qw + b * 16384 +
                              (qf * 64 + w * 16 + lo) * 64 + ks * 32 + hi * 8);

    f32x4 o[4][4];                     // [qf][mf(h)] O^T accumulators
    #pragma unroll
    for (int qf = 0; qf < 4; ++qf)
        #pragma unroll
        for (int mf = 0; mf < 4; ++mf)
            o[qf][mf] = (f32x4){0.f, 0.f, 0.f, 0.f};
    float m2[4]   = {-INFINITY, -INFINITY, -INFINITY, -INFINITY};
    float lsum[4] = {0.f, 0.f, 0.f, 0.f};

    const float SC = 0.125f * 1.44269504088896340736f;  // scale * log2(e)

    #pragma unroll
    for (int kc = 0; kc < 4; ++kc) {
        // V^T frags for this key chunk (reused across qf)
        bf16x8 vf[4][2];
        #pragma unroll
        for (int mf = 0; mf < 4; ++mf)
            #pragma unroll
            for (int ks = 0; ks < 2; ++ks)
                vf[mf][ks] = *(const bf16x8*)(VTw + (b * 64 + mf * 16 + lo) * 256 +
                                              kc * 64 + ks * 32 + hi * 8);

        #pragma unroll
        for (int qf = kc; qf < 4; ++qf) {
            // S^T chunk: 4 key-frags x (K=64 dims as 2 slices)
            f32x4 s[4];
            #pragma unroll
            for (int kf = 0; kf < 4; ++kf) {
                bf16x8 k0 = *(const bf16x8*)&Klds[kc * 64 + kf * 16 + lo][hi * 8];
                bf16x8 k1 = *(const bf16x8*)&Klds[kc * 64 + kf * 16 + lo][32 + hi * 8];
                f32x4 t = (f32x4){0.f, 0.f, 0.f, 0.f};
                t = MFMA16(k0, qfr[qf][0], t);
                t = MFMA16(k1, qfr[qf][1], t);
                s[kf] = t;
            }
            // scale + causal mask (diag chunk only) + lane-local max
            float mx = -INFINITY;
            #pragma unroll
            for (int kf = 0; kf < 4; ++kf)
                #pragma unroll
                for (int i = 0; i < 4; ++i) {
                    float v = s[kf][i] * SC;
                    if (kc == qf && (kf * 16 + hi * 4 + i) > (w * 16 + lo)) v = -INFINITY;
                    s[kf][i] = v;
                    mx = fmaxf(mx, v);
                }
            mx = fmaxf(mx, __shfl_xor(mx, 16));
            mx = fmaxf(mx, __shfl_xor(mx, 32));
            const float mnew = fmaxf(m2[qf], mx);
            const float rsc  = exp2f(m2[qf] - mnew);   // 0 on first chunk
            m2[qf] = mnew;

            float cs = 0.f;
            bf16x4 pk[4];
            #pragma unroll
            for (int kf = 0; kf < 4; ++kf)
                #pragma unroll
                for (int i = 0; i < 4; ++i) {
                    float p = exp2f(s[kf][i] - mnew);
                    cs += p;
                    pk[kf][i] = (bf16)p;
                }
            cs += __shfl_xor(cs, 16);
            cs += __shfl_xor(cs, 32);
            lsum[qf] = lsum[qf] * rsc + cs;

            // P -> LDS [q=lo][key]: lane's 4 values are consecutive keys (8B store)
            #pragma unroll
            for (int kf = 0; kf < 4; ++kf)
                *(bf16x4*)&Plds[w][lo][kf * 16 + hi * 4] = pk[kf];

            // rescale O accumulators
            #pragma unroll
            for (int mf = 0; mf < 4; ++mf) {
                o[qf][mf][0] *= rsc; o[qf][mf][1] *= rsc;
                o[qf][mf][2] *= rsc; o[qf][mf][3] *= rsc;
            }
            // PV: O^T += V^T * P^T   (P-frag read: [q=lo][ks*32+hi*8 ..+8])
            #pragma unroll
            for (int ks = 0; ks < 2; ++ks) {
                bf16x8 pf = *(const bf16x8*)&Plds[w][lo][ks * 32 + hi * 8];
                #pragma unroll
                for (int mf = 0; mf < 4; ++mf)
                    o[qf][mf] = MFMA16(vf[mf][ks], pf, o[qf][mf]);
            }
        }
    }

    // Epilogue: out[b][q][h] fp32; lane's 4 values are consecutive h -> 16B store
    #pragma unroll
    for (int qf = 0; qf < 4; ++qf) {
        const float inv = 1.0f / lsum[qf];
        const int q = qf * 64 + w * 16 + lo;
        #pragma unroll
        for (int mf = 0; mf < 4; ++mf) {
            f32x4 r4;
            r4[0] = o[qf][mf][0] * inv; r4[1] = o[qf][mf][1] * inv;
            r4[2] = o[qf][mf][2] * inv; r4[3] = o[qf][mf][3] * inv;
            *(f32x4*)(out + (b * 256 + q) * 64 + mf * 16 + hi * 4) = r4;
        }
    }
}

// ---------------- launcher --------------------------------------------------
extern "C" void kernel_launch(void* const* d_in, const int* in_sizes, int n_in,
                              void* d_out, int out_size, void* d_ws, size_t ws_size,
                              hipStream_t stream) {
    const float* x  = (const float*)d_in[0];
    const float* Wq = (const float*)d_in[1];
    const float* Wk = (const float*)d_in[2];
    const float* Wv = (const float*)d_in[3];
    float* out = (float*)d_out;

    char* ws = (char*)d_ws;
    bf16* WT  = (bf16*)(ws);
    bf16* Qw  = (bf16*)(ws + 196608);
    bf16* Kw  = (bf16*)(ws + 16973824);
    bf16* VTw = (bf16*)(ws + 33751040);

    wt_transpose_kernel<<<dim3(384), dim3(256), 0, stream>>>(Wq, Wk, Wv, WT);
    proj_kernel<<<dim3(1024), dim3(256), 0, stream>>>(x, WT, Qw, Kw, VTw);
    attn_kernel<<<dim3(512), dim3(256), 0, stream>>>(Qw, Kw, VTw, out);
}